// Round 7
// baseline (23517.923 us; speedup 1.0000x reference)
//
#include <hip/hip_runtime.h>

#define NN 8000
#define EE 200000
#define BB 16
#define DD 256
#define LL 4
#define KF 600

typedef unsigned short bf16;

__device__ __forceinline__ float b2f(bf16 u) { return __uint_as_float(((unsigned)u) << 16); }
__device__ __forceinline__ bf16 f2b(float f) {
    unsigned u = __float_as_uint(f);
    u = u + 0x7fffu + ((u >> 16) & 1u);
    return (bf16)(u >> 16);
}

// feature j of [sin(2*pi*f*d_c) | cos(2*pi*f*d_c)], j in [0,600)
__device__ __forceinline__ float fval(float d0, float d1, float d2, int j) {
    int jj = (j < 300) ? j : j - 300;
    int c = jj / 100;
    int f = jj - c * 100;
    float d = (c == 0) ? d0 : ((c == 1) ? d1 : d2);
    float ang = 6.283185307179586f * d * (float)f;
    return (j < 300) ? sinf(ang) : cosf(ang);
}

// ---------------- setup ----------------

__global__ void k_lfeat(const float* __restrict__ lat, float* __restrict__ lf) {
    int t = threadIdx.x;
    if (t >= BB * 6) return;
    int b = t / 6, p = t % 6;
    const int rr[6] = {0, 0, 0, 1, 1, 2};
    const int cc[6] = {0, 1, 2, 1, 2, 2};
    float acc = 0.f;
    for (int i = 0; i < 3; i++)
        acc += lat[b * 9 + i * 3 + rr[p]] * lat[b * 9 + i * 3 + cc[p]];
    lf[b * 6 + p] = acc;
}

__global__ void k_zero(int* __restrict__ p, int n) {
    int i = blockIdx.x * 256 + threadIdx.x;
    if (i < n) p[i] = 0;
}

__global__ void k_zerof(float* __restrict__ p, int n) {
    int i = blockIdx.x * 256 + threadIdx.x;
    if (i < n) p[i] = 0.f;
}

__global__ void k_count(const int* __restrict__ src, int* __restrict__ counts) {
    int e = blockIdx.x * 256 + threadIdx.x;
    if (e < EE) atomicAdd(&counts[src[e]], 1);
}

__global__ void k_scan(const int* __restrict__ counts, int* __restrict__ starts,
                       int* __restrict__ cursor) {
    __shared__ int ssum[256];
    int tid = threadIdx.x;
    int base = tid * 32;
    int local = 0;
    for (int i = 0; i < 32; i++) {
        int r = base + i;
        if (r < NN) local += counts[r];
    }
    ssum[tid] = local;
    __syncthreads();
    for (int off = 1; off < 256; off <<= 1) {
        int v = (tid >= off) ? ssum[tid - off] : 0;
        __syncthreads();
        ssum[tid] += v;
        __syncthreads();
    }
    int run = (tid == 0) ? 0 : ssum[tid - 1];
    for (int i = 0; i < 32; i++) {
        int r = base + i;
        if (r < NN) {
            starts[r] = run;
            cursor[r] = run;
            run += counts[r];
        }
    }
    if (tid == 255) starts[NN] = ssum[255];
}

__global__ void k_scatter(const int* __restrict__ src, int* __restrict__ cursor,
                          int* __restrict__ eids) {
    int e = blockIdx.x * 256 + threadIdx.x;
    if (e >= EE) return;
    int pos = atomicAdd(&cursor[src[e]], 1);
    eids[pos] = e;
}

__global__ void k_node_init(const int* __restrict__ at, const int* __restrict__ bid,
                            const float* __restrict__ emb, const float* __restrict__ W,
                            const float* __restrict__ nb, const float* __restrict__ lf,
                            float* __restrict__ hn) {
    __shared__ float arow[262];
    int n = blockIdx.x, d = threadIdx.x;
    arow[d] = emb[at[n] * DD + d];
    if (d < 6) arow[256 + d] = lf[bid[n] * 6 + d];
    __syncthreads();
    float acc = nb[d];
    for (int k = 0; k < 262; k++) acc += arow[k] * W[k * DD + d];
    hn[n * DD + d] = acc;
}

// ---------------- literal QK: per 64-edge tile, h_e tile then Q,K, scores ----------------

__global__ void __launch_bounds__(256) k_qk_lit(
    const float* __restrict__ hn, const int* __restrict__ src, const int* __restrict__ dst,
    const float* __restrict__ frac, const float* __restrict__ shifts,
    const float* __restrict__ We, const float* __restrict__ be,
    const float* __restrict__ Wq, const float* __restrict__ bq,
    const float* __restrict__ Wkv, const float* __restrict__ bkv,
    float* __restrict__ scores) {
    __shared__ float dsv[64][3];
    __shared__ int sid[64], did[64];
    __shared__ bf16 heb[64][256];
    __shared__ float As[64][9];
    __shared__ float Ak[64][9];
    __shared__ float Bq[8][256];
    __shared__ float Bk[8][256];
    int tid = threadIdx.x, tx = tid & 15, ty = tid >> 4;
    int e0 = blockIdx.x * 64;
    if (tid < 64) {
        int e = e0 + tid;
        int s = src[e], d = dst[e];
        sid[tid] = s; did[tid] = d;
#pragma unroll
        for (int c = 0; c < 3; c++) {
            float a = frac[d * 3 + c] - frac[s * 3 + c] + shifts[e * 3 + c];
            dsv[tid][c] = a - floorf(a);
        }
    }
    __syncthreads();
    int ar = tid >> 2, ac = (tid & 3) * 2;
    float d0 = dsv[ar][0], d1 = dsv[ar][1], d2 = dsv[ar][2];
    int bwr = tid >> 5, bwc = (tid & 31) * 8;

    // stage 1: he = F @ We + be
    {
        float acc[4][4][4] = {};
        for (int k0 = 0; k0 < KF; k0 += 8) {
            As[ar][ac + 0] = fval(d0, d1, d2, k0 + ac + 0);
            As[ar][ac + 1] = fval(d0, d1, d2, k0 + ac + 1);
            float4 w0 = *(const float4*)&We[(k0 + bwr) * 256 + bwc];
            float4 w1 = *(const float4*)&We[(k0 + bwr) * 256 + bwc + 4];
            *(float4*)&Bq[bwr][bwc] = w0;
            *(float4*)&Bq[bwr][bwc + 4] = w1;
            __syncthreads();
#pragma unroll
            for (int kk = 0; kk < 8; kk++) {
                float a[4];
#pragma unroll
                for (int i = 0; i < 4; i++) a[i] = As[ty * 4 + i][kk];
#pragma unroll
                for (int g = 0; g < 4; g++)
#pragma unroll
                    for (int j = 0; j < 4; j++) {
                        float b = Bq[kk][g * 64 + tx * 4 + j];
#pragma unroll
                        for (int i = 0; i < 4; i++) acc[i][g][j] += a[i] * b;
                    }
            }
            __syncthreads();
        }
#pragma unroll
        for (int i = 0; i < 4; i++) {
            int row = ty * 4 + i;
#pragma unroll
            for (int g = 0; g < 4; g++)
#pragma unroll
                for (int j = 0; j < 4; j++) {
                    int col = g * 64 + tx * 4 + j;
                    heb[row][col] = f2b(acc[i][g][j] + be[col]);
                }
        }
    }
    __syncthreads();

    // stage 2: Q = [hn[src]|he]@Wq, K = [hn[dst]|he]@Wkv[:, :256]
    float aQ[4][4][4] = {}, aK[4][4][4] = {};
    for (int k0 = 0; k0 < 512; k0 += 8) {
        if (k0 < 256) {
            int gs = sid[ar], gd = did[ar];
            float2 q2 = *(const float2*)&hn[gs * DD + k0 + ac];
            As[ar][ac] = q2.x; As[ar][ac + 1] = q2.y;
            float2 k2 = *(const float2*)&hn[gd * DD + k0 + ac];
            Ak[ar][ac] = k2.x; Ak[ar][ac + 1] = k2.y;
        } else {
            float v0 = b2f(heb[ar][k0 - 256 + ac]);
            float v1 = b2f(heb[ar][k0 - 256 + ac + 1]);
            As[ar][ac] = v0; As[ar][ac + 1] = v1;
            Ak[ar][ac] = v0; Ak[ar][ac + 1] = v1;
        }
        float4 wq0 = *(const float4*)&Wq[(size_t)(k0 + bwr) * 256 + bwc];
        float4 wq1 = *(const float4*)&Wq[(size_t)(k0 + bwr) * 256 + bwc + 4];
        *(float4*)&Bq[bwr][bwc] = wq0;
        *(float4*)&Bq[bwr][bwc + 4] = wq1;
        float4 wk0 = *(const float4*)&Wkv[(size_t)(k0 + bwr) * 512 + bwc];
        float4 wk1 = *(const float4*)&Wkv[(size_t)(k0 + bwr) * 512 + bwc + 4];
        *(float4*)&Bk[bwr][bwc] = wk0;
        *(float4*)&Bk[bwr][bwc + 4] = wk1;
        __syncthreads();
#pragma unroll
        for (int kk = 0; kk < 8; kk++) {
            float aq[4], ak[4];
#pragma unroll
            for (int i = 0; i < 4; i++) { aq[i] = As[ty * 4 + i][kk]; ak[i] = Ak[ty * 4 + i][kk]; }
#pragma unroll
            for (int g = 0; g < 4; g++)
#pragma unroll
                for (int j = 0; j < 4; j++) {
                    float bq_ = Bq[kk][g * 64 + tx * 4 + j];
                    float bk_ = Bk[kk][g * 64 + tx * 4 + j];
#pragma unroll
                    for (int i = 0; i < 4; i++) {
                        aQ[i][g][j] += aq[i] * bq_;
                        aK[i][g][j] += ak[i] * bk_;
                    }
                }
        }
        __syncthreads();
    }
#pragma unroll
    for (int i = 0; i < 4; i++) {
        int e = e0 + ty * 4 + i;
#pragma unroll
        for (int g = 0; g < 4; g++) {
            float s = 0.f;
#pragma unroll
            for (int j = 0; j < 4; j++) {
                int col = g * 64 + tx * 4 + j;
                s += (aQ[i][g][j] + bq[col]) * (aK[i][g][j] + bkv[col]);
            }
            s += __shfl_xor(s, 1, 64);
            s += __shfl_xor(s, 2, 64);
            s += __shfl_xor(s, 4, 64);
            s += __shfl_xor(s, 8, 64);
            if (tx == 0) scores[e * 4 + g] = s * 0.125f;
        }
    }
}

// ---------------- literal AV: per 64-edge tile, h_e tile, V tile, atomic scatter ----------------

__global__ void __launch_bounds__(256) k_av_lit(
    const float* __restrict__ hn, const int* __restrict__ src, const int* __restrict__ dst,
    const float* __restrict__ frac, const float* __restrict__ shifts,
    const float* __restrict__ We, const float* __restrict__ be,
    const float* __restrict__ Wkv, const float* __restrict__ bkv,
    const float* __restrict__ w, float* __restrict__ attn) {
    __shared__ float dsv[64][3];
    __shared__ int sid[64], did[64];
    __shared__ bf16 heb[64][256];
    __shared__ float As[64][9];
    __shared__ float Bv[8][256];
    int tid = threadIdx.x, tx = tid & 15, ty = tid >> 4;
    int e0 = blockIdx.x * 64;
    if (tid < 64) {
        int e = e0 + tid;
        int s = src[e], d = dst[e];
        sid[tid] = s; did[tid] = d;
#pragma unroll
        for (int c = 0; c < 3; c++) {
            float a = frac[d * 3 + c] - frac[s * 3 + c] + shifts[e * 3 + c];
            dsv[tid][c] = a - floorf(a);
        }
    }
    __syncthreads();
    int ar = tid >> 2, ac = (tid & 3) * 2;
    float d0 = dsv[ar][0], d1 = dsv[ar][1], d2 = dsv[ar][2];
    int bwr = tid >> 5, bwc = (tid & 31) * 8;

    // stage 1: he
    {
        float acc[4][4][4] = {};
        for (int k0 = 0; k0 < KF; k0 += 8) {
            As[ar][ac + 0] = fval(d0, d1, d2, k0 + ac + 0);
            As[ar][ac + 1] = fval(d0, d1, d2, k0 + ac + 1);
            float4 w0 = *(const float4*)&We[(k0 + bwr) * 256 + bwc];
            float4 w1 = *(const float4*)&We[(k0 + bwr) * 256 + bwc + 4];
            *(float4*)&Bv[bwr][bwc] = w0;
            *(float4*)&Bv[bwr][bwc + 4] = w1;
            __syncthreads();
#pragma unroll
            for (int kk = 0; kk < 8; kk++) {
                float a[4];
#pragma unroll
                for (int i = 0; i < 4; i++) a[i] = As[ty * 4 + i][kk];
#pragma unroll
                for (int g = 0; g < 4; g++)
#pragma unroll
                    for (int j = 0; j < 4; j++) {
                        float b = Bv[kk][g * 64 + tx * 4 + j];
#pragma unroll
                        for (int i = 0; i < 4; i++) acc[i][g][j] += a[i] * b;
                    }
            }
            __syncthreads();
        }
#pragma unroll
        for (int i = 0; i < 4; i++) {
            int row = ty * 4 + i;
#pragma unroll
            for (int g = 0; g < 4; g++)
#pragma unroll
                for (int j = 0; j < 4; j++) {
                    int col = g * 64 + tx * 4 + j;
                    heb[row][col] = f2b(acc[i][g][j] + be[col]);
                }
        }
    }
    __syncthreads();

    // stage 2: V = [hn[dst]|he] @ Wkv[:, 256:] + bkv[256:]
    float aV[4][4][4] = {};
    for (int k0 = 0; k0 < 512; k0 += 8) {
        if (k0 < 256) {
            int gd = did[ar];
            float2 k2 = *(const float2*)&hn[gd * DD + k0 + ac];
            As[ar][ac] = k2.x; As[ar][ac + 1] = k2.y;
        } else {
            As[ar][ac] = b2f(heb[ar][k0 - 256 + ac]);
            As[ar][ac + 1] = b2f(heb[ar][k0 - 256 + ac + 1]);
        }
        float4 wv0 = *(const float4*)&Wkv[(size_t)(k0 + bwr) * 512 + 256 + bwc];
        float4 wv1 = *(const float4*)&Wkv[(size_t)(k0 + bwr) * 512 + 256 + bwc + 4];
        *(float4*)&Bv[bwr][bwc] = wv0;
        *(float4*)&Bv[bwr][bwc + 4] = wv1;
        __syncthreads();
#pragma unroll
        for (int kk = 0; kk < 8; kk++) {
            float a[4];
#pragma unroll
            for (int i = 0; i < 4; i++) a[i] = As[ty * 4 + i][kk];
#pragma unroll
            for (int g = 0; g < 4; g++)
#pragma unroll
                for (int j = 0; j < 4; j++) {
                    float b = Bv[kk][g * 64 + tx * 4 + j];
#pragma unroll
                    for (int i = 0; i < 4; i++) aV[i][g][j] += a[i] * b;
                }
        }
        __syncthreads();
    }
#pragma unroll
    for (int i = 0; i < 4; i++) {
        int row = ty * 4 + i;
        int e = e0 + row;
        int srow = sid[row];
#pragma unroll
        for (int g = 0; g < 4; g++) {
            float wv = w[e * 4 + g];
#pragma unroll
            for (int j = 0; j < 4; j++) {
                int col = g * 64 + tx * 4 + j;
                float v = aV[i][g][j] + bkv[256 + col];
                atomicAdd(&attn[srow * DD + col], wv * v);
            }
        }
    }
}

// ---------------- segment softmax ----------------

__global__ void k_softmax(const int* __restrict__ starts, const int* __restrict__ eids,
                          float* __restrict__ scores) {
    int n = blockIdx.x;
    int s0 = starts[n], s1 = starts[n + 1];
    int h = threadIdx.x >> 6, lane = threadIdx.x & 63;
    float mx = -1e30f;
    for (int i = s0 + lane; i < s1; i += 64) mx = fmaxf(mx, scores[eids[i] * 4 + h]);
    for (int m = 32; m >= 1; m >>= 1) mx = fmaxf(mx, __shfl_xor(mx, m, 64));
    float den = 0.f;
    for (int i = s0 + lane; i < s1; i += 64) den += expf(scores[eids[i] * 4 + h] - mx);
    for (int m = 32; m >= 1; m >>= 1) den += __shfl_xor(den, m, 64);
    float inv = 1.0f / den;
    for (int i = s0 + lane; i < s1; i += 64) {
        int e = eids[i];
        scores[e * 4 + h] = expf(scores[e * 4 + h] - mx) * inv;
    }
}

// ---------------- node GEMM (A fp32 stride DD, W fp32) ----------------

__global__ void k_gemm_node(const float* __restrict__ A, const float* __restrict__ W,
                            int ldw, const float* __restrict__ bias, float* __restrict__ C,
                            int act, int accum) {
    __shared__ float As[64][17];
    __shared__ float Bs[16][64];
    int tid = threadIdx.x;
    int tx = tid & 15, ty = tid >> 4;
    int m0 = blockIdx.x * 64, n0 = blockIdx.y * 64;
    int arow = tid >> 2, akb = (tid & 3) * 4;
    int bkk = tid >> 4, bnn = (tid & 15) * 4;
    float acc[4][4] = {};
    for (int k0 = 0; k0 < 256; k0 += 16) {
        float4 av = *(const float4*)&A[(m0 + arow) * DD + k0 + akb];
        As[arow][akb + 0] = av.x; As[arow][akb + 1] = av.y;
        As[arow][akb + 2] = av.z; As[arow][akb + 3] = av.w;
        float4 bv = *(const float4*)&W[(size_t)(k0 + bkk) * ldw + n0 + bnn];
        Bs[bkk][bnn + 0] = bv.x; Bs[bkk][bnn + 1] = bv.y;
        Bs[bkk][bnn + 2] = bv.z; Bs[bkk][bnn + 3] = bv.w;
        __syncthreads();
#pragma unroll
        for (int kk = 0; kk < 16; kk++) {
            float a[4], b[4];
#pragma unroll
            for (int i = 0; i < 4; i++) a[i] = As[ty * 4 + i][kk];
#pragma unroll
            for (int j = 0; j < 4; j++) b[j] = Bs[kk][tx * 4 + j];
#pragma unroll
            for (int i = 0; i < 4; i++)
#pragma unroll
                for (int j = 0; j < 4; j++) acc[i][j] += a[i] * b[j];
        }
        __syncthreads();
    }
#pragma unroll
    for (int i = 0; i < 4; i++) {
        int m = m0 + ty * 4 + i;
#pragma unroll
        for (int j = 0; j < 4; j++) {
            int col = n0 + tx * 4 + j;
            float v = acc[i][j] + (bias ? bias[col] : 0.f);
            if (act) v = 0.5f * v * (1.0f + erff(v * 0.7071067811865475f));
            if (accum) v += C[m * DD + col];
            C[m * DD + col] = v;
        }
    }
}

// ---------------- residual + layernorm ----------------

__global__ void k_add_ln(float* __restrict__ h, const float* __restrict__ r,
                         const float* __restrict__ g, const float* __restrict__ b) {
    __shared__ float red[4];
    int n = blockIdx.x, d = threadIdx.x;
    float x = h[n * DD + d] + r[n * DD + d];
    float v = x;
    for (int m = 32; m >= 1; m >>= 1) v += __shfl_xor(v, m, 64);
    if ((d & 63) == 0) red[d >> 6] = v;
    __syncthreads();
    float mu = (red[0] + red[1] + red[2] + red[3]) * (1.0f / 256.0f);
    __syncthreads();
    float t = x - mu;
    v = t * t;
    for (int m = 32; m >= 1; m >>= 1) v += __shfl_xor(v, m, 64);
    if ((d & 63) == 0) red[d >> 6] = v;
    __syncthreads();
    float var = (red[0] + red[1] + red[2] + red[3]) * (1.0f / 256.0f);
    h[n * DD + d] = t * rsqrtf(var + 1e-5f) * g[d] + b[d];
}

// output is FP32 (reference h_n is float32; inputs proven fp32 by the r2/r3 NaN signature)
__global__ void k_out(const float* __restrict__ h, float* __restrict__ out) {
    int i = blockIdx.x * 256 + threadIdx.x;
    if (i < NN * DD) out[i] = h[i];
}

// ---------------- launch ----------------

extern "C" void kernel_launch(void* const* d_in, const int* in_sizes, int n_in,
                              void* d_out, int out_size, void* d_ws, size_t ws_size,
                              hipStream_t stream) {
    const int* atom_types = (const int*)d_in[0];
    const float* lattices = (const float*)d_in[1];
    const float* frac = (const float*)d_in[2];
    const int* eidx = (const int*)d_in[3];
    const float* shifts = (const float*)d_in[4];
    const int* batch_ids = (const int*)d_in[5];
    const float* atom_emb = (const float*)d_in[6];
    const float* node_W = (const float*)d_in[7];
    const float* node_b = (const float*)d_in[8];
    const float* edge_W = (const float*)d_in[9];
    const float* edge_b = (const float*)d_in[10];
    const float* Wq = (const float*)d_in[11];
    const float* bq = (const float*)d_in[12];
    const float* Wkv = (const float*)d_in[13];
    const float* bkv = (const float*)d_in[14];
    const float* Wo = (const float*)d_in[15];
    const float* bo = (const float*)d_in[16];
    const float* ln1g = (const float*)d_in[17];
    const float* ln1b = (const float*)d_in[18];
    const float* W1 = (const float*)d_in[19];
    const float* b1 = (const float*)d_in[20];
    const float* W2 = (const float*)d_in[21];
    const float* b2w = (const float*)d_in[22];
    const float* ln2g = (const float*)d_in[23];
    const float* ln2b = (const float*)d_in[24];

    char* base = (char*)d_ws;
    size_t off = 0;
    auto alloc = [&](size_t bytes) -> void* {
        void* p = base + off;
        off = (off + bytes + 255) & ~(size_t)255;
        return p;
    };
    // total ~25.5 MB
    int* counts = (int*)alloc((size_t)NN * 4);
    int* cursor = (int*)alloc((size_t)NN * 4);
    int* starts = (int*)alloc((size_t)(NN + 1) * 4);
    int* eids = (int*)alloc((size_t)EE * 4);
    float* lfeat = (float*)alloc((size_t)BB * 6 * 4);
    float* h_n = (float*)alloc((size_t)NN * DD * 4);
    float* attn = (float*)alloc((size_t)NN * DD * 4);  // reused as h1 chunk
    float* tmp = (float*)alloc((size_t)NN * DD * 4);   // also aliases scores (E*4 floats)
    float* scores = tmp;  // lifetimes disjoint within a layer

    const int* src = eidx;
    const int* dstp = eidx + EE;

    k_lfeat<<<1, 96, 0, stream>>>(lattices, lfeat);
    k_zero<<<(NN + 255) / 256, 256, 0, stream>>>(counts, NN);
    k_count<<<(EE + 255) / 256, 256, 0, stream>>>(src, counts);
    k_scan<<<1, 256, 0, stream>>>(counts, starts, cursor);
    k_scatter<<<(EE + 255) / 256, 256, 0, stream>>>(src, cursor, eids);
    k_node_init<<<NN, 256, 0, stream>>>(atom_types, batch_ids, atom_emb, node_W, node_b,
                                        lfeat, h_n);

    for (int l = 0; l < LL; l++) {
        const float* Wql = Wq + (size_t)l * 512 * 256;
        const float* bql = bq + l * 256;
        const float* Wkvl = Wkv + (size_t)l * 512 * 512;
        const float* bkvl = bkv + l * 512;
        k_qk_lit<<<EE / 64, 256, 0, stream>>>(h_n, src, dstp, frac, shifts, edge_W, edge_b,
                                              Wql, bql, Wkvl, bkvl, scores);
        k_softmax<<<NN, 256, 0, stream>>>(starts, eids, scores);
        k_zerof<<<(NN * DD + 255) / 256, 256, 0, stream>>>(attn, NN * DD);
        k_av_lit<<<EE / 64, 256, 0, stream>>>(h_n, src, dstp, frac, shifts, edge_W, edge_b,
                                              Wkvl, bkvl, scores, attn);
        k_gemm_node<<<dim3(NN / 64, 4), 256, 0, stream>>>(attn, Wo + (size_t)l * 256 * 256,
                                                          256, bo + l * 256, tmp, 0, 0);
        k_add_ln<<<NN, 256, 0, stream>>>(h_n, tmp, ln1g + l * 256, ln1b + l * 256);
        for (int c = 0; c < 4; c++) {
            k_gemm_node<<<dim3(NN / 64, 4), 256, 0, stream>>>(
                h_n, W1 + (size_t)l * 256 * 1024 + c * 256, 1024, b1 + l * 1024 + c * 256,
                attn, 1, 0);
            k_gemm_node<<<dim3(NN / 64, 4), 256, 0, stream>>>(
                attn, W2 + (size_t)l * 1024 * 256 + (size_t)c * 256 * 256, 256,
                (c == 0) ? (b2w + l * 256) : (const float*)nullptr, tmp, 0, (c == 0) ? 0 : 1);
        }
        k_add_ln<<<NN, 256, 0, stream>>>(h_n, tmp, ln2g + l * 256, ln2b + l * 256);
    }
    k_out<<<(NN * DD + 255) / 256, 256, 0, stream>>>(h_n, (float*)d_out);
}

// Round 8
// 5572.536 us; speedup vs baseline: 4.2203x; 4.2203x over previous
//
#include <hip/hip_runtime.h>

#define NN 8000
#define EE 200000
#define BB 16
#define DD 256
#define LL 4
#define KF 600
#define HEPAD 272

typedef unsigned short bf16;
typedef short bf16x8 __attribute__((ext_vector_type(8)));
typedef float f32x4 __attribute__((ext_vector_type(4)));

__device__ __forceinline__ float b2f(bf16 u) { return __uint_as_float(((unsigned)u) << 16); }
__device__ __forceinline__ bf16 f2b(float f) {
    unsigned u = __float_as_uint(f);
    u = u + 0x7fffu + ((u >> 16) & 1u);
    return (bf16)(u >> 16);
}

__device__ __forceinline__ float fval(float d0, float d1, float d2, int j) {
    int jj = (j < 300) ? j : j - 300;
    int c = jj / 100;
    int f = jj - c * 100;
    float d = (c == 0) ? d0 : ((c == 1) ? d1 : d2);
    float ang = 6.283185307179586f * d * (float)f;
    return (j < 300) ? sinf(ang) : cosf(ang);
}

// ---------------- setup ----------------

__global__ void k_lfeat(const float* __restrict__ lat, float* __restrict__ lf) {
    int t = threadIdx.x;
    if (t >= BB * 6) return;
    int b = t / 6, p = t % 6;
    const int rr[6] = {0, 0, 0, 1, 1, 2};
    const int cc[6] = {0, 1, 2, 1, 2, 2};
    float acc = 0.f;
    for (int i = 0; i < 3; i++)
        acc += lat[b * 9 + i * 3 + rr[p]] * lat[b * 9 + i * 3 + cc[p]];
    lf[b * 6 + p] = acc;
}

__global__ void k_zero(int* __restrict__ p, int n) {
    int i = blockIdx.x * 256 + threadIdx.x;
    if (i < n) p[i] = 0;
}

__global__ void k_zerof(float* __restrict__ p, int n) {
    int i = blockIdx.x * 256 + threadIdx.x;
    if (i < n) p[i] = 0.f;
}

__global__ void k_count(const int* __restrict__ src, int* __restrict__ counts) {
    int e = blockIdx.x * 256 + threadIdx.x;
    if (e < EE) atomicAdd(&counts[src[e]], 1);
}

__global__ void k_scan(const int* __restrict__ counts, int* __restrict__ starts,
                       int* __restrict__ cursor) {
    __shared__ int ssum[256];
    int tid = threadIdx.x;
    int base = tid * 32;
    int local = 0;
    for (int i = 0; i < 32; i++) {
        int r = base + i;
        if (r < NN) local += counts[r];
    }
    ssum[tid] = local;
    __syncthreads();
    for (int off = 1; off < 256; off <<= 1) {
        int v = (tid >= off) ? ssum[tid - off] : 0;
        __syncthreads();
        ssum[tid] += v;
        __syncthreads();
    }
    int run = (tid == 0) ? 0 : ssum[tid - 1];
    for (int i = 0; i < 32; i++) {
        int r = base + i;
        if (r < NN) {
            starts[r] = run;
            cursor[r] = run;
            run += counts[r];
        }
    }
    if (tid == 255) starts[NN] = ssum[255];
}

__global__ void k_scatter(const int* __restrict__ src, int* __restrict__ cursor,
                          int* __restrict__ eids) {
    int e = blockIdx.x * 256 + threadIdx.x;
    if (e >= EE) return;
    int pos = atomicAdd(&cursor[src[e]], 1);
    eids[pos] = e;
}

__global__ void k_node_init(const int* __restrict__ at, const int* __restrict__ bid,
                            const float* __restrict__ emb, const float* __restrict__ W,
                            const float* __restrict__ nb, const float* __restrict__ lf,
                            float* __restrict__ hn) {
    __shared__ float arow[262];
    int n = blockIdx.x, d = threadIdx.x;
    arow[d] = emb[at[n] * DD + d];
    if (d < 6) arow[256 + d] = lf[bid[n] * 6 + d];
    __syncthreads();
    float acc = nb[d];
    for (int k = 0; k < 262; k++) acc += arow[k] * W[k * DD + d];
    hn[n * DD + d] = acc;
}

__global__ void k_cvt(const float* __restrict__ hn, bf16* __restrict__ hnb, int n) {
    int i = blockIdx.x * 256 + threadIdx.x;
    if (i < n) hnb[i] = f2b(hn[i]);
}

// ---------------- weight panel tiling (bf16, Wt[p][n][kk]) ----------------

__global__ void k_panel_we(const float* __restrict__ We, bf16* __restrict__ WeP) {
    int p = blockIdx.x, n = threadIdx.x;  // p 0..18, n 0..255
    for (int kk = 0; kk < 32; kk++) {
        int k = p * 32 + kk;
        float v = (k < KF) ? We[k * 256 + n] : 0.f;
        WeP[((size_t)p * 256 + n) * 32 + kk] = f2b(v);
    }
}

__global__ void k_panel_w(const float* __restrict__ W, int ldw, int c0,
                          bf16* __restrict__ dst) {
    int p = blockIdx.x, l = blockIdx.y, n = threadIdx.x;  // p 0..15
    const float* Wl = W + (size_t)l * 512 * ldw;
    bf16* dl = dst + (size_t)l * 16 * 8192;
    for (int kk = 0; kk < 32; kk++) {
        int k = p * 32 + kk;
        dl[((size_t)p * 256 + n) * 32 + kk] = f2b(Wl[(size_t)k * ldw + c0 + n]);
    }
}

// ---------------- MFMA QK kernel ----------------

__global__ void __launch_bounds__(256) k_qk_mfma(
    const bf16* __restrict__ hnb, const int* __restrict__ src, const int* __restrict__ dst,
    const float* __restrict__ frac, const float* __restrict__ shifts,
    const uint4* __restrict__ WeP, const float* __restrict__ be,
    const uint4* __restrict__ QP, const uint4* __restrict__ KP,
    const float* __restrict__ bq, const float* __restrict__ bkv,
    float* __restrict__ scores) {
    __shared__ bf16 heb[64][HEPAD];
    __shared__ bf16 As[2][64][32];
    __shared__ uint4 Bs[1024];
    __shared__ float dsv[64][3];
    __shared__ int sid[64], did[64];

    int tid = threadIdx.x;
    int wv = tid >> 6, lane = tid & 63, quad = lane >> 4, m = lane & 15;
    int e0 = blockIdx.x * 64;
    if (tid < 64) {
        int e = e0 + tid;
        int sn = src[e], dn = dst[e];
        sid[tid] = sn; did[tid] = dn;
#pragma unroll
        for (int c = 0; c < 3; c++) {
            float a = frac[dn * 3 + c] - frac[sn * 3 + c] + shifts[e * 3 + c];
            dsv[tid][c] = a - floorf(a);
        }
    }
    __syncthreads();

    int ar = tid >> 2, kb = (tid & 3) * 8;
    float d0 = dsv[ar][0], d1 = dsv[ar][1], d2 = dsv[ar][2];
    const bf16* bsu = (const bf16*)Bs;

    // ---- stage 1: he = F @ We + be (MFMA), K=608 (19 ksteps)
    {
        f32x4 acc1[16];
#pragma unroll
        for (int t = 0; t < 16; t++) acc1[t] = (f32x4){0.f, 0.f, 0.f, 0.f};
        for (int p = 0; p < 19; p++) {
#pragma unroll
            for (int j = 0; j < 8; j++) {
                int k = p * 32 + kb + j;
                As[0][ar][kb + j] = (k < KF) ? f2b(fval(d0, d1, d2, k)) : (bf16)0;
            }
            const uint4* gsrc = WeP + (size_t)p * 1024;
#pragma unroll
            for (int i = 0; i < 4; i++) Bs[tid + i * 256] = gsrc[tid + i * 256];
            __syncthreads();
            bf16x8 a = *(const bf16x8*)&As[0][16 * wv + m][quad * 8];
#pragma unroll
            for (int t = 0; t < 16; t++) {
                int cg = t >> 2, su = t & 3;
                bf16x8 b = *(const bf16x8*)&bsu[cg * 2048 + (su * 16 + m) * 32 + quad * 8];
                acc1[t] = __builtin_amdgcn_mfma_f32_16x16x32_bf16(a, b, acc1[t], 0, 0, 0);
            }
            __syncthreads();
        }
#pragma unroll
        for (int t = 0; t < 16; t++) {
            int col = (t >> 2) * 64 + (t & 3) * 16 + m;
            float bias = be[col];
#pragma unroll
            for (int r = 0; r < 4; r++)
                heb[16 * wv + quad * 4 + r][col] = f2b(acc1[t][r] + bias);
        }
    }
    __syncthreads();

    // ---- stage 2: per head, Q and K via MFMA, fused score dot
    for (int h = 0; h < 4; h++) {
        f32x4 qa[4], ka[4];
#pragma unroll
        for (int s = 0; s < 4; s++) { qa[s] = (f32x4){0.f,0.f,0.f,0.f}; ka[s] = (f32x4){0.f,0.f,0.f,0.f}; }
        for (int p = 0; p < 16; p++) {
            if (p < 8) {
                *(uint4*)&As[0][ar][kb] = *(const uint4*)&hnb[(size_t)sid[ar] * 256 + p * 32 + kb];
                *(uint4*)&As[1][ar][kb] = *(const uint4*)&hnb[(size_t)did[ar] * 256 + p * 32 + kb];
            }
            Bs[tid] = QP[(size_t)(p * 4 + h) * 256 + tid];
            Bs[256 + tid] = KP[(size_t)(p * 4 + h) * 256 + tid];
            __syncthreads();
            bf16x8 aq, ad;
            if (p < 8) {
                aq = *(const bf16x8*)&As[0][16 * wv + m][quad * 8];
                ad = *(const bf16x8*)&As[1][16 * wv + m][quad * 8];
            } else {
                bf16x8 t8 = *(const bf16x8*)&heb[16 * wv + m][(p - 8) * 32 + quad * 8];
                aq = t8; ad = t8;
            }
#pragma unroll
            for (int s = 0; s < 4; s++) {
                bf16x8 b1 = *(const bf16x8*)&bsu[(s * 16 + m) * 32 + quad * 8];
                qa[s] = __builtin_amdgcn_mfma_f32_16x16x32_bf16(aq, b1, qa[s], 0, 0, 0);
                bf16x8 b2 = *(const bf16x8*)&bsu[2048 + (s * 16 + m) * 32 + quad * 8];
                ka[s] = __builtin_amdgcn_mfma_f32_16x16x32_bf16(ad, b2, ka[s], 0, 0, 0);
            }
            __syncthreads();
        }
        float qb[4], kb2[4];
#pragma unroll
        for (int s = 0; s < 4; s++) {
            int col = h * 64 + s * 16 + m;
            qb[s] = bq[col];
            kb2[s] = bkv[col];
        }
        float p4[4];
#pragma unroll
        for (int r = 0; r < 4; r++) {
            float sum = 0.f;
#pragma unroll
            for (int s = 0; s < 4; s++) sum += (qa[s][r] + qb[s]) * (ka[s][r] + kb2[s]);
            p4[r] = sum;
        }
#pragma unroll
        for (int r = 0; r < 4; r++) {
            p4[r] += __shfl_xor(p4[r], 1, 64);
            p4[r] += __shfl_xor(p4[r], 2, 64);
            p4[r] += __shfl_xor(p4[r], 4, 64);
            p4[r] += __shfl_xor(p4[r], 8, 64);
        }
        if (m == 0) {
#pragma unroll
            for (int r = 0; r < 4; r++)
                scores[(size_t)(e0 + 16 * wv + quad * 4 + r) * 4 + h] = p4[r] * 0.125f;
        }
    }
}

// ---------------- MFMA AV kernel ----------------

__global__ void __launch_bounds__(256) k_av_mfma(
    const bf16* __restrict__ hnb, const int* __restrict__ src, const int* __restrict__ dst,
    const float* __restrict__ frac, const float* __restrict__ shifts,
    const uint4* __restrict__ WeP, const float* __restrict__ be,
    const uint4* __restrict__ VP, const float* __restrict__ bkv,
    const float* __restrict__ w, float* __restrict__ attn) {
    __shared__ bf16 heb[64][HEPAD];
    __shared__ bf16 As[64][32];
    __shared__ uint4 Bs[1024];
    __shared__ float dsv[64][3];
    __shared__ int sid[64], did[64];

    int tid = threadIdx.x;
    int wv = tid >> 6, lane = tid & 63, quad = lane >> 4, m = lane & 15;
    int e0 = blockIdx.x * 64;
    if (tid < 64) {
        int e = e0 + tid;
        int sn = src[e], dn = dst[e];
        sid[tid] = sn; did[tid] = dn;
#pragma unroll
        for (int c = 0; c < 3; c++) {
            float a = frac[dn * 3 + c] - frac[sn * 3 + c] + shifts[e * 3 + c];
            dsv[tid][c] = a - floorf(a);
        }
    }
    __syncthreads();

    int ar = tid >> 2, kb = (tid & 3) * 8;
    float d0 = dsv[ar][0], d1 = dsv[ar][1], d2 = dsv[ar][2];
    const bf16* bsu = (const bf16*)Bs;

    // ---- stage 1: he (same as qk)
    {
        f32x4 acc1[16];
#pragma unroll
        for (int t = 0; t < 16; t++) acc1[t] = (f32x4){0.f, 0.f, 0.f, 0.f};
        for (int p = 0; p < 19; p++) {
#pragma unroll
            for (int j = 0; j < 8; j++) {
                int k = p * 32 + kb + j;
                As[ar][kb + j] = (k < KF) ? f2b(fval(d0, d1, d2, k)) : (bf16)0;
            }
            const uint4* gsrc = WeP + (size_t)p * 1024;
#pragma unroll
            for (int i = 0; i < 4; i++) Bs[tid + i * 256] = gsrc[tid + i * 256];
            __syncthreads();
            bf16x8 a = *(const bf16x8*)&As[16 * wv + m][quad * 8];
#pragma unroll
            for (int t = 0; t < 16; t++) {
                int cg = t >> 2, su = t & 3;
                bf16x8 b = *(const bf16x8*)&bsu[cg * 2048 + (su * 16 + m) * 32 + quad * 8];
                acc1[t] = __builtin_amdgcn_mfma_f32_16x16x32_bf16(a, b, acc1[t], 0, 0, 0);
            }
            __syncthreads();
        }
#pragma unroll
        for (int t = 0; t < 16; t++) {
            int col = (t >> 2) * 64 + (t & 3) * 16 + m;
            float bias = be[col];
#pragma unroll
            for (int r = 0; r < 4; r++)
                heb[16 * wv + quad * 4 + r][col] = f2b(acc1[t][r] + bias);
        }
    }
    __syncthreads();

    // ---- stage 2: V = [hnb[dst]|he] @ Wv
    f32x4 va[16];
#pragma unroll
    for (int t = 0; t < 16; t++) va[t] = (f32x4){0.f, 0.f, 0.f, 0.f};
    for (int p = 0; p < 16; p++) {
        if (p < 8)
            *(uint4*)&As[ar][kb] = *(const uint4*)&hnb[(size_t)did[ar] * 256 + p * 32 + kb];
        const uint4* gsrc = VP + (size_t)p * 1024;
#pragma unroll
        for (int i = 0; i < 4; i++) Bs[tid + i * 256] = gsrc[tid + i * 256];
        __syncthreads();
        bf16x8 a;
        if (p < 8) a = *(const bf16x8*)&As[16 * wv + m][quad * 8];
        else a = *(const bf16x8*)&heb[16 * wv + m][(p - 8) * 32 + quad * 8];
#pragma unroll
        for (int t = 0; t < 16; t++) {
            int cg = t >> 2, su = t & 3;
            bf16x8 b = *(const bf16x8*)&bsu[cg * 2048 + (su * 16 + m) * 32 + quad * 8];
            va[t] = __builtin_amdgcn_mfma_f32_16x16x32_bf16(a, b, va[t], 0, 0, 0);
        }
        __syncthreads();
    }
    // epilogue: weighted atomic scatter into attn[src]
    float wrow[4][4];  // [r][h]
#pragma unroll
    for (int r = 0; r < 4; r++) {
        int e = e0 + 16 * wv + quad * 4 + r;
#pragma unroll
        for (int h = 0; h < 4; h++) wrow[r][h] = w[(size_t)e * 4 + h];
    }
#pragma unroll
    for (int t = 0; t < 16; t++) {
        int col = (t >> 2) * 64 + (t & 3) * 16 + m;
        int h = t >> 2;
        float vb = bkv[256 + col];
#pragma unroll
        for (int r = 0; r < 4; r++) {
            int row = 16 * wv + quad * 4 + r;
            atomicAdd(&attn[(size_t)sid[row] * 256 + col], wrow[r][h] * (va[t][r] + vb));
        }
    }
}

// ---------------- segment softmax ----------------

__global__ void k_softmax(const int* __restrict__ starts, const int* __restrict__ eids,
                          float* __restrict__ scores) {
    int n = blockIdx.x;
    int s0 = starts[n], s1 = starts[n + 1];
    int h = threadIdx.x >> 6, lane = threadIdx.x & 63;
    float mx = -1e30f;
    for (int i = s0 + lane; i < s1; i += 64) mx = fmaxf(mx, scores[eids[i] * 4 + h]);
    for (int m = 32; m >= 1; m >>= 1) mx = fmaxf(mx, __shfl_xor(mx, m, 64));
    float den = 0.f;
    for (int i = s0 + lane; i < s1; i += 64) den += expf(scores[eids[i] * 4 + h] - mx);
    for (int m = 32; m >= 1; m >>= 1) den += __shfl_xor(den, m, 64);
    float inv = 1.0f / den;
    for (int i = s0 + lane; i < s1; i += 64) {
        int e = eids[i];
        scores[e * 4 + h] = expf(scores[e * 4 + h] - mx) * inv;
    }
}

// ---------------- node GEMM (fp32) ----------------

__global__ void k_gemm_node(const float* __restrict__ A, const float* __restrict__ W,
                            int ldw, const float* __restrict__ bias, float* __restrict__ C,
                            int act, int accum) {
    __shared__ float As[64][17];
    __shared__ float Bs[16][64];
    int tid = threadIdx.x;
    int tx = tid & 15, ty = tid >> 4;
    int m0 = blockIdx.x * 64, n0 = blockIdx.y * 64;
    int arow = tid >> 2, akb = (tid & 3) * 4;
    int bkk = tid >> 4, bnn = (tid & 15) * 4;
    float acc[4][4] = {};
    for (int k0 = 0; k0 < 256; k0 += 16) {
        float4 av = *(const float4*)&A[(m0 + arow) * DD + k0 + akb];
        As[arow][akb + 0] = av.x; As[arow][akb + 1] = av.y;
        As[arow][akb + 2] = av.z; As[arow][akb + 3] = av.w;
        float4 bv = *(const float4*)&W[(size_t)(k0 + bkk) * ldw + n0 + bnn];
        Bs[bkk][bnn + 0] = bv.x; Bs[bkk][bnn + 1] = bv.y;
        Bs[bkk][bnn + 2] = bv.z; Bs[bkk][bnn + 3] = bv.w;
        __syncthreads();
#pragma unroll
        for (int kk = 0; kk < 16; kk++) {
            float a[4], b[4];
#pragma unroll
            for (int i = 0; i < 4; i++) a[i] = As[ty * 4 + i][kk];
#pragma unroll
            for (int j = 0; j < 4; j++) b[j] = Bs[kk][tx * 4 + j];
#pragma unroll
            for (int i = 0; i < 4; i++)
#pragma unroll
                for (int j = 0; j < 4; j++) acc[i][j] += a[i] * b[j];
        }
        __syncthreads();
    }
#pragma unroll
    for (int i = 0; i < 4; i++) {
        int mm = m0 + ty * 4 + i;
#pragma unroll
        for (int j = 0; j < 4; j++) {
            int col = n0 + tx * 4 + j;
            float v = acc[i][j] + (bias ? bias[col] : 0.f);
            if (act) v = 0.5f * v * (1.0f + erff(v * 0.7071067811865475f));
            if (accum) v += C[mm * DD + col];
            C[mm * DD + col] = v;
        }
    }
}

// ---------------- residual + layernorm ----------------

__global__ void k_add_ln(float* __restrict__ h, const float* __restrict__ r,
                         const float* __restrict__ g, const float* __restrict__ b) {
    __shared__ float red[4];
    int n = blockIdx.x, d = threadIdx.x;
    float x = h[n * DD + d] + r[n * DD + d];
    float v = x;
    for (int m = 32; m >= 1; m >>= 1) v += __shfl_xor(v, m, 64);
    if ((d & 63) == 0) red[d >> 6] = v;
    __syncthreads();
    float mu = (red[0] + red[1] + red[2] + red[3]) * (1.0f / 256.0f);
    __syncthreads();
    float t = x - mu;
    v = t * t;
    for (int m = 32; m >= 1; m >>= 1) v += __shfl_xor(v, m, 64);
    if ((d & 63) == 0) red[d >> 6] = v;
    __syncthreads();
    float var = (red[0] + red[1] + red[2] + red[3]) * (1.0f / 256.0f);
    h[n * DD + d] = t * rsqrtf(var + 1e-5f) * g[d] + b[d];
}

__global__ void k_out(const float* __restrict__ h, float* __restrict__ out) {
    int i = blockIdx.x * 256 + threadIdx.x;
    if (i < NN * DD) out[i] = h[i];
}

// ---------------- launch ----------------

extern "C" void kernel_launch(void* const* d_in, const int* in_sizes, int n_in,
                              void* d_out, int out_size, void* d_ws, size_t ws_size,
                              hipStream_t stream) {
    const int* atom_types = (const int*)d_in[0];
    const float* lattices = (const float*)d_in[1];
    const float* frac = (const float*)d_in[2];
    const int* eidx = (const int*)d_in[3];
    const float* shifts = (const float*)d_in[4];
    const int* batch_ids = (const int*)d_in[5];
    const float* atom_emb = (const float*)d_in[6];
    const float* node_W = (const float*)d_in[7];
    const float* node_b = (const float*)d_in[8];
    const float* edge_W = (const float*)d_in[9];
    const float* edge_b = (const float*)d_in[10];
    const float* Wq = (const float*)d_in[11];
    const float* bq = (const float*)d_in[12];
    const float* Wkv = (const float*)d_in[13];
    const float* bkv = (const float*)d_in[14];
    const float* Wo = (const float*)d_in[15];
    const float* bo = (const float*)d_in[16];
    const float* ln1g = (const float*)d_in[17];
    const float* ln1b = (const float*)d_in[18];
    const float* W1 = (const float*)d_in[19];
    const float* b1 = (const float*)d_in[20];
    const float* W2 = (const float*)d_in[21];
    const float* b2w = (const float*)d_in[22];
    const float* ln2g = (const float*)d_in[23];
    const float* ln2b = (const float*)d_in[24];

    char* base = (char*)d_ws;
    size_t off = 0;
    auto alloc = [&](size_t bytes) -> void* {
        void* p = base + off;
        off = (off + bytes + 255) & ~(size_t)255;
        return p;
    };
    // ~33 MB total
    int* counts = (int*)alloc((size_t)NN * 4);
    int* cursor = (int*)alloc((size_t)NN * 4);
    int* starts = (int*)alloc((size_t)(NN + 1) * 4);
    int* eids = (int*)alloc((size_t)EE * 4);
    float* lfeat = (float*)alloc((size_t)BB * 6 * 4);
    float* h_n = (float*)alloc((size_t)NN * DD * 4);
    float* attn = (float*)alloc((size_t)NN * DD * 4);
    float* tmp = (float*)alloc((size_t)NN * DD * 4);
    float* scores = tmp;  // disjoint lifetimes within a layer
    bf16* hnb = (bf16*)alloc((size_t)NN * DD * 2);
    bf16* WeP = (bf16*)alloc((size_t)19 * 8192 * 2);
    bf16* QP = (bf16*)alloc((size_t)LL * 16 * 8192 * 2);
    bf16* KP = (bf16*)alloc((size_t)LL * 16 * 8192 * 2);
    bf16* VP = (bf16*)alloc((size_t)LL * 16 * 8192 * 2);

    const int* src = eidx;
    const int* dstp = eidx + EE;

    k_lfeat<<<1, 96, 0, stream>>>(lattices, lfeat);
    k_zero<<<(NN + 255) / 256, 256, 0, stream>>>(counts, NN);
    k_count<<<(EE + 255) / 256, 256, 0, stream>>>(src, counts);
    k_scan<<<1, 256, 0, stream>>>(counts, starts, cursor);
    k_scatter<<<(EE + 255) / 256, 256, 0, stream>>>(src, cursor, eids);
    k_node_init<<<NN, 256, 0, stream>>>(atom_types, batch_ids, atom_emb, node_W, node_b,
                                        lfeat, h_n);
    k_cvt<<<(NN * DD + 255) / 256, 256, 0, stream>>>(h_n, hnb, NN * DD);
    k_panel_we<<<19, 256, 0, stream>>>(edge_W, WeP);
    k_panel_w<<<dim3(16, LL), 256, 0, stream>>>(Wq, 256, 0, QP);
    k_panel_w<<<dim3(16, LL), 256, 0, stream>>>(Wkv, 512, 0, KP);
    k_panel_w<<<dim3(16, LL), 256, 0, stream>>>(Wkv, 512, 256, VP);

    for (int l = 0; l < LL; l++) {
        const uint4* QPl = (const uint4*)(QP + (size_t)l * 16 * 8192);
        const uint4* KPl = (const uint4*)(KP + (size_t)l * 16 * 8192);
        const uint4* VPl = (const uint4*)(VP + (size_t)l * 16 * 8192);
        const float* bql = bq + l * 256;
        const float* bkvl = bkv + l * 512;
        k_qk_mfma<<<EE / 64, 256, 0, stream>>>(hnb, src, dstp, frac, shifts,
                                               (const uint4*)WeP, edge_b, QPl, KPl,
                                               bql, bkvl, scores);
        k_softmax<<<NN, 256, 0, stream>>>(starts, eids, scores);
        k_zerof<<<(NN * DD + 255) / 256, 256, 0, stream>>>(attn, NN * DD);
        k_av_mfma<<<EE / 64, 256, 0, stream>>>(hnb, src, dstp, frac, shifts,
                                               (const uint4*)WeP, edge_b, VPl,
                                               bkvl, scores, attn);
        k_gemm_node<<<dim3(NN / 64, 4), 256, 0, stream>>>(attn, Wo + (size_t)l * 256 * 256,
                                                          256, bo + l * 256, tmp, 0, 0);
        k_add_ln<<<NN, 256, 0, stream>>>(h_n, tmp, ln1g + l * 256, ln1b + l * 256);
        for (int c = 0; c < 4; c++) {
            k_gemm_node<<<dim3(NN / 64, 4), 256, 0, stream>>>(
                h_n, W1 + (size_t)l * 256 * 1024 + c * 256, 1024, b1 + l * 1024 + c * 256,
                attn, 1, 0);
            k_gemm_node<<<dim3(NN / 64, 4), 256, 0, stream>>>(
                attn, W2 + (size_t)l * 1024 * 256 + (size_t)c * 256 * 256, 256,
                (c == 0) ? (b2w + l * 256) : (const float*)nullptr, tmp, 0, (c == 0) ? 0 : 1);
        }
        k_add_ln<<<NN, 256, 0, stream>>>(h_n, tmp, ln2g + l * 256, ln2b + l * 256);
        k_cvt<<<(NN * DD + 255) / 256, 256, 0, stream>>>(h_n, hnb, NN * DD);
    }
    k_out<<<(NN * DD + 255) / 256, 256, 0, stream>>>(h_n, (float*)d_out);
}

// Round 9
// 4705.750 us; speedup vs baseline: 4.9977x; 1.1842x over previous
//
#include <hip/hip_runtime.h>

#define NN 8000
#define EE 200000
#define BB 16
#define DD 256
#define LL 4
#define KF 600
#define HEPAD 280
#define ASPAD 40

typedef unsigned short bf16;
typedef short bf16x8 __attribute__((ext_vector_type(8)));
typedef float f32x4 __attribute__((ext_vector_type(4)));

__device__ __forceinline__ float b2f(bf16 u) { return __uint_as_float(((unsigned)u) << 16); }
__device__ __forceinline__ bf16 f2b(float f) {
    unsigned u = __float_as_uint(f);
    u = u + 0x7fffu + ((u >> 16) & 1u);
    return (bf16)(u >> 16);
}

__device__ __forceinline__ float fval(float d0, float d1, float d2, int j) {
    int jj = (j < 300) ? j : j - 300;
    int c = jj / 100;
    int f = jj - c * 100;
    float d = (c == 0) ? d0 : ((c == 1) ? d1 : d2);
    float ang = 6.283185307179586f * d * (float)f;
    return (j < 300) ? sinf(ang) : cosf(ang);
}

// b-fragment read from a swizzled 256x32 panel in LDS: n = t*16+m, kblk swizzled
__device__ __forceinline__ bf16x8 bfrag(const bf16* bsu, int t, int m, int quad) {
    int q2 = (quad + ((m >> 1) & 3)) & 3;
    return *(const bf16x8*)&bsu[(t * 16 + m) * 32 + q2 * 8];
}

// ---------------- setup ----------------

__global__ void k_lfeat(const float* __restrict__ lat, float* __restrict__ lf) {
    int t = threadIdx.x;
    if (t >= BB * 6) return;
    int b = t / 6, p = t % 6;
    const int rr[6] = {0, 0, 0, 1, 1, 2};
    const int cc[6] = {0, 1, 2, 1, 2, 2};
    float acc = 0.f;
    for (int i = 0; i < 3; i++)
        acc += lat[b * 9 + i * 3 + rr[p]] * lat[b * 9 + i * 3 + cc[p]];
    lf[b * 6 + p] = acc;
}

__global__ void k_zero(int* __restrict__ p, int n) {
    int i = blockIdx.x * 256 + threadIdx.x;
    if (i < n) p[i] = 0;
}

__global__ void k_zerof(float* __restrict__ p, int n) {
    int i = blockIdx.x * 256 + threadIdx.x;
    if (i < n) p[i] = 0.f;
}

__global__ void k_count(const int* __restrict__ src, int* __restrict__ counts) {
    int e = blockIdx.x * 256 + threadIdx.x;
    if (e < EE) atomicAdd(&counts[src[e]], 1);
}

__global__ void k_scan(const int* __restrict__ counts, int* __restrict__ starts,
                       int* __restrict__ cursor) {
    __shared__ int ssum[256];
    int tid = threadIdx.x;
    int base = tid * 32;
    int local = 0;
    for (int i = 0; i < 32; i++) {
        int r = base + i;
        if (r < NN) local += counts[r];
    }
    ssum[tid] = local;
    __syncthreads();
    for (int off = 1; off < 256; off <<= 1) {
        int v = (tid >= off) ? ssum[tid - off] : 0;
        __syncthreads();
        ssum[tid] += v;
        __syncthreads();
    }
    int run = (tid == 0) ? 0 : ssum[tid - 1];
    for (int i = 0; i < 32; i++) {
        int r = base + i;
        if (r < NN) {
            starts[r] = run;
            cursor[r] = run;
            run += counts[r];
        }
    }
    if (tid == 255) starts[NN] = ssum[255];
}

__global__ void k_scatter(const int* __restrict__ src, int* __restrict__ cursor,
                          int* __restrict__ eids) {
    int e = blockIdx.x * 256 + threadIdx.x;
    if (e >= EE) return;
    int pos = atomicAdd(&cursor[src[e]], 1);
    eids[pos] = e;
}

__global__ void k_node_init(const int* __restrict__ at, const int* __restrict__ bid,
                            const float* __restrict__ emb, const float* __restrict__ W,
                            const float* __restrict__ nb, const float* __restrict__ lf,
                            float* __restrict__ hn) {
    __shared__ float arow[262];
    int n = blockIdx.x, d = threadIdx.x;
    arow[d] = emb[at[n] * DD + d];
    if (d < 6) arow[256 + d] = lf[bid[n] * 6 + d];
    __syncthreads();
    float acc = nb[d];
    for (int k = 0; k < 262; k++) acc += arow[k] * W[k * DD + d];
    hn[n * DD + d] = acc;
}

__global__ void k_cvt(const float* __restrict__ src, bf16* __restrict__ dst, int n) {
    int i = blockIdx.x * 256 + threadIdx.x;
    if (i < n) dst[i] = f2b(src[i]);
}

// ---------------- swizzled panel builder ----------------
// panel p: rows k in [p*32, p*32+32), cols c0 + g*256 + n; elem = n*32 + swz(kk,n)

__global__ void k_panel(const float* __restrict__ W, int ldw, int c0, size_t wlstride,
                        int Ktot, bf16* __restrict__ dst, int pcount) {
    int p = blockIdx.x, l = blockIdx.y, g = blockIdx.z, n = threadIdx.x;
    const float* Wl = W + (size_t)l * wlstride;
    bf16* d = dst + (((size_t)(l * gridDim.z + g)) * pcount + p) * 8192;
    int c = c0 + g * 256 + n;
    for (int kk = 0; kk < 32; kk++) {
        int k = p * 32 + kk;
        float v = (k < Ktot) ? Wl[(size_t)k * ldw + c] : 0.f;
        int swz = ((((kk >> 3) + ((n >> 1) & 3)) & 3)) * 8 + (kk & 7);
        d[n * 32 + swz] = f2b(v);
    }
}

// ---------------- MFMA QK kernel ----------------

__global__ void __launch_bounds__(256) k_qk_mfma(
    const bf16* __restrict__ hnb, const int* __restrict__ src, const int* __restrict__ dst,
    const float* __restrict__ frac, const float* __restrict__ shifts,
    const uint4* __restrict__ WeP, const float* __restrict__ be,
    const uint4* __restrict__ QP, const uint4* __restrict__ KP,
    const float* __restrict__ bq, const float* __restrict__ bkv,
    float* __restrict__ scores) {
    __shared__ bf16 heb[64][HEPAD];
    __shared__ bf16 As[64][ASPAD];
    __shared__ uint4 Bs[1024];
    __shared__ float dsv[64][3];
    __shared__ int sid[64], did[64];

    int tid = threadIdx.x;
    int wv = tid >> 6, lane = tid & 63, quad = lane >> 4, m = lane & 15;
    int e0 = blockIdx.x * 64;
    if (tid < 64) {
        int e = e0 + tid;
        int sn = src[e], dn = dst[e];
        sid[tid] = sn; did[tid] = dn;
#pragma unroll
        for (int c = 0; c < 3; c++) {
            float a = frac[dn * 3 + c] - frac[sn * 3 + c] + shifts[e * 3 + c];
            dsv[tid][c] = a - floorf(a);
        }
    }
    __syncthreads();

    int ar = tid >> 2, kb = (tid & 3) * 8;
    float d0 = dsv[ar][0], d1 = dsv[ar][1], d2 = dsv[ar][2];
    const bf16* bsu = (const bf16*)Bs;

    // ---- stage 1: he = F @ We + be
    {
        f32x4 acc1[16];
#pragma unroll
        for (int t = 0; t < 16; t++) acc1[t] = (f32x4){0.f, 0.f, 0.f, 0.f};
        for (int p = 0; p < 19; p++) {
            bf16 t8[8];
#pragma unroll
            for (int j = 0; j < 8; j++) {
                int k = p * 32 + kb + j;
                t8[j] = (k < KF) ? f2b(fval(d0, d1, d2, k)) : (bf16)0;
            }
            *(uint4*)&As[ar][kb] = *(const uint4*)t8;
#pragma unroll
            for (int i = 0; i < 4; i++) Bs[tid + i * 256] = WeP[(size_t)p * 1024 + tid + i * 256];
            __syncthreads();
            bf16x8 a = *(const bf16x8*)&As[16 * wv + m][quad * 8];
#pragma unroll
            for (int t = 0; t < 16; t++)
                acc1[t] = __builtin_amdgcn_mfma_f32_16x16x32_bf16(a, bfrag(bsu, t, m, quad),
                                                                  acc1[t], 0, 0, 0);
            __syncthreads();
        }
#pragma unroll
        for (int t = 0; t < 16; t++) {
            int col = t * 16 + m;
            float bias = be[col];
#pragma unroll
            for (int r = 0; r < 4; r++)
                heb[16 * wv + quad * 4 + r][col] = f2b(acc1[t][r] + bias);
        }
    }
    __syncthreads();

    // ---- stage 2a: Q = [hnb[src]|he] @ Wq
    f32x4 qa[16];
#pragma unroll
    for (int t = 0; t < 16; t++) qa[t] = (f32x4){0.f, 0.f, 0.f, 0.f};
    for (int p = 0; p < 16; p++) {
        if (p < 8)
            *(uint4*)&As[ar][kb] = *(const uint4*)&hnb[(size_t)sid[ar] * 256 + p * 32 + kb];
#pragma unroll
        for (int i = 0; i < 4; i++) Bs[tid + i * 256] = QP[(size_t)p * 1024 + tid + i * 256];
        __syncthreads();
        bf16x8 a = (p < 8) ? *(const bf16x8*)&As[16 * wv + m][quad * 8]
                           : *(const bf16x8*)&heb[16 * wv + m][(p - 8) * 32 + quad * 8];
#pragma unroll
        for (int t = 0; t < 16; t++)
            qa[t] = __builtin_amdgcn_mfma_f32_16x16x32_bf16(a, bfrag(bsu, t, m, quad),
                                                            qa[t], 0, 0, 0);
        __syncthreads();
    }
    // ---- stage 2b: K = [hnb[dst]|he] @ Wkv[:, :256]
    f32x4 ka[16];
#pragma unroll
    for (int t = 0; t < 16; t++) ka[t] = (f32x4){0.f, 0.f, 0.f, 0.f};
    for (int p = 0; p < 16; p++) {
        if (p < 8)
            *(uint4*)&As[ar][kb] = *(const uint4*)&hnb[(size_t)did[ar] * 256 + p * 32 + kb];
#pragma unroll
        for (int i = 0; i < 4; i++) Bs[tid + i * 256] = KP[(size_t)p * 1024 + tid + i * 256];
        __syncthreads();
        bf16x8 a = (p < 8) ? *(const bf16x8*)&As[16 * wv + m][quad * 8]
                           : *(const bf16x8*)&heb[16 * wv + m][(p - 8) * 32 + quad * 8];
#pragma unroll
        for (int t = 0; t < 16; t++)
            ka[t] = __builtin_amdgcn_mfma_f32_16x16x32_bf16(a, bfrag(bsu, t, m, quad),
                                                            ka[t], 0, 0, 0);
        __syncthreads();
    }
    // ---- epilogue: scores
#pragma unroll
    for (int h = 0; h < 4; h++) {
        float p4[4];
#pragma unroll
        for (int r = 0; r < 4; r++) {
            float sum = 0.f;
#pragma unroll
            for (int ss = 0; ss < 4; ss++) {
                int t = h * 4 + ss;
                int col = t * 16 + m;
                sum += (qa[t][r] + bq[col]) * (ka[t][r] + bkv[col]);
            }
            p4[r] = sum;
        }
#pragma unroll
        for (int r = 0; r < 4; r++) {
            p4[r] += __shfl_xor(p4[r], 1, 64);
            p4[r] += __shfl_xor(p4[r], 2, 64);
            p4[r] += __shfl_xor(p4[r], 4, 64);
            p4[r] += __shfl_xor(p4[r], 8, 64);
        }
        if (m == 0) {
#pragma unroll
            for (int r = 0; r < 4; r++)
                scores[(size_t)(e0 + 16 * wv + quad * 4 + r) * 4 + h] = p4[r] * 0.125f;
        }
    }
}

// ---------------- MFMA AV kernel ----------------

__global__ void __launch_bounds__(256) k_av_mfma(
    const bf16* __restrict__ hnb, const int* __restrict__ src, const int* __restrict__ dst,
    const float* __restrict__ frac, const float* __restrict__ shifts,
    const uint4* __restrict__ WeP, const float* __restrict__ be,
    const uint4* __restrict__ VP, const float* __restrict__ bkv,
    const float* __restrict__ w, float* __restrict__ attn) {
    __shared__ bf16 heb[64][HEPAD];
    __shared__ bf16 As[64][ASPAD];
    __shared__ uint4 Bs[1024];
    __shared__ float dsv[64][3];
    __shared__ int sid[64], did[64];

    int tid = threadIdx.x;
    int wv = tid >> 6, lane = tid & 63, quad = lane >> 4, m = lane & 15;
    int e0 = blockIdx.x * 64;
    if (tid < 64) {
        int e = e0 + tid;
        int sn = src[e], dn = dst[e];
        sid[tid] = sn; did[tid] = dn;
#pragma unroll
        for (int c = 0; c < 3; c++) {
            float a = frac[dn * 3 + c] - frac[sn * 3 + c] + shifts[e * 3 + c];
            dsv[tid][c] = a - floorf(a);
        }
    }
    __syncthreads();

    int ar = tid >> 2, kb = (tid & 3) * 8;
    float d0 = dsv[ar][0], d1 = dsv[ar][1], d2 = dsv[ar][2];
    const bf16* bsu = (const bf16*)Bs;

    // ---- stage 1: he
    {
        f32x4 acc1[16];
#pragma unroll
        for (int t = 0; t < 16; t++) acc1[t] = (f32x4){0.f, 0.f, 0.f, 0.f};
        for (int p = 0; p < 19; p++) {
            bf16 t8[8];
#pragma unroll
            for (int j = 0; j < 8; j++) {
                int k = p * 32 + kb + j;
                t8[j] = (k < KF) ? f2b(fval(d0, d1, d2, k)) : (bf16)0;
            }
            *(uint4*)&As[ar][kb] = *(const uint4*)t8;
#pragma unroll
            for (int i = 0; i < 4; i++) Bs[tid + i * 256] = WeP[(size_t)p * 1024 + tid + i * 256];
            __syncthreads();
            bf16x8 a = *(const bf16x8*)&As[16 * wv + m][quad * 8];
#pragma unroll
            for (int t = 0; t < 16; t++)
                acc1[t] = __builtin_amdgcn_mfma_f32_16x16x32_bf16(a, bfrag(bsu, t, m, quad),
                                                                  acc1[t], 0, 0, 0);
            __syncthreads();
        }
#pragma unroll
        for (int t = 0; t < 16; t++) {
            int col = t * 16 + m;
            float bias = be[col];
#pragma unroll
            for (int r = 0; r < 4; r++)
                heb[16 * wv + quad * 4 + r][col] = f2b(acc1[t][r] + bias);
        }
    }
    __syncthreads();

    // ---- stage 2: V = [hnb[dst]|he] @ Wkv[:, 256:]
    f32x4 va[16];
#pragma unroll
    for (int t = 0; t < 16; t++) va[t] = (f32x4){0.f, 0.f, 0.f, 0.f};
    for (int p = 0; p < 16; p++) {
        if (p < 8)
            *(uint4*)&As[ar][kb] = *(const uint4*)&hnb[(size_t)did[ar] * 256 + p * 32 + kb];
#pragma unroll
        for (int i = 0; i < 4; i++) Bs[tid + i * 256] = VP[(size_t)p * 1024 + tid + i * 256];
        __syncthreads();
        bf16x8 a = (p < 8) ? *(const bf16x8*)&As[16 * wv + m][quad * 8]
                           : *(const bf16x8*)&heb[16 * wv + m][(p - 8) * 32 + quad * 8];
#pragma unroll
        for (int t = 0; t < 16; t++)
            va[t] = __builtin_amdgcn_mfma_f32_16x16x32_bf16(a, bfrag(bsu, t, m, quad),
                                                            va[t], 0, 0, 0);
        __syncthreads();
    }
    // epilogue: weighted atomic scatter into attn[src]
    float wrow[4][4];
#pragma unroll
    for (int r = 0; r < 4; r++) {
        int e = e0 + 16 * wv + quad * 4 + r;
#pragma unroll
        for (int h = 0; h < 4; h++) wrow[r][h] = w[(size_t)e * 4 + h];
    }
#pragma unroll
    for (int t = 0; t < 16; t++) {
        int col = t * 16 + m;
        int h = t >> 2;
        float vb = bkv[256 + col];
#pragma unroll
        for (int r = 0; r < 4; r++) {
            int row = 16 * wv + quad * 4 + r;
            atomicAdd(&attn[(size_t)sid[row] * 256 + col], wrow[r][h] * (va[t][r] + vb));
        }
    }
}

// ---------------- node GEMM via MFMA (32-row tiles, 128 threads) ----------------

template <int OUTB>
__global__ void __launch_bounds__(128) k_gnode(
    const bf16* __restrict__ Ab, int lda, const uint4* __restrict__ P, int ksteps,
    const float* __restrict__ bias, int act, float* __restrict__ Cf,
    bf16* __restrict__ Cb, int ldc) {
    __shared__ bf16 As[32][ASPAD];
    __shared__ uint4 Bs[1024];
    int tid = threadIdx.x;
    int wv = tid >> 6, lane = tid & 63, quad = lane >> 4, m = lane & 15;
    int m0 = blockIdx.x * 32, g = blockIdx.y;
    const uint4* Pg = P + (size_t)g * ksteps * 1024;
    const bf16* bsu = (const bf16*)Bs;
    int ar = tid >> 2, kb = (tid & 3) * 8;
    f32x4 acc[16];
#pragma unroll
    for (int t = 0; t < 16; t++) acc[t] = (f32x4){0.f, 0.f, 0.f, 0.f};
    for (int p = 0; p < ksteps; p++) {
        *(uint4*)&As[ar][kb] = *(const uint4*)&Ab[(size_t)(m0 + ar) * lda + p * 32 + kb];
#pragma unroll
        for (int i = 0; i < 8; i++) Bs[tid + i * 128] = Pg[(size_t)p * 1024 + tid + i * 128];
        __syncthreads();
        bf16x8 a = *(const bf16x8*)&As[16 * wv + m][quad * 8];
#pragma unroll
        for (int t = 0; t < 16; t++)
            acc[t] = __builtin_amdgcn_mfma_f32_16x16x32_bf16(a, bfrag(bsu, t, m, quad),
                                                             acc[t], 0, 0, 0);
        __syncthreads();
    }
#pragma unroll
    for (int t = 0; t < 16; t++) {
        int col = g * 256 + t * 16 + m;
        float bb = bias ? bias[col] : 0.f;
#pragma unroll
        for (int r = 0; r < 4; r++) {
            int row = m0 + 16 * wv + quad * 4 + r;
            float v = acc[t][r] + bb;
            if (act) v = 0.5f * v * (1.0f + erff(v * 0.7071067811865475f));
            if (OUTB) Cb[(size_t)row * ldc + col] = f2b(v);
            else Cf[(size_t)row * ldc + col] = v;
        }
    }
}

// ---------------- segment softmax ----------------

__global__ void k_softmax(const int* __restrict__ starts, const int* __restrict__ eids,
                          float* __restrict__ scores) {
    int n = blockIdx.x;
    int s0 = starts[n], s1 = starts[n + 1];
    int h = threadIdx.x >> 6, lane = threadIdx.x & 63;
    float mx = -1e30f;
    for (int i = s0 + lane; i < s1; i += 64) mx = fmaxf(mx, scores[eids[i] * 4 + h]);
    for (int m = 32; m >= 1; m >>= 1) mx = fmaxf(mx, __shfl_xor(mx, m, 64));
    float den = 0.f;
    for (int i = s0 + lane; i < s1; i += 64) den += expf(scores[eids[i] * 4 + h] - mx);
    for (int m = 32; m >= 1; m >>= 1) den += __shfl_xor(den, m, 64);
    float inv = 1.0f / den;
    for (int i = s0 + lane; i < s1; i += 64) {
        int e = eids[i];
        scores[e * 4 + h] = expf(scores[e * 4 + h] - mx) * inv;
    }
}

// ---------------- residual + layernorm ----------------

__global__ void k_add_ln(float* __restrict__ h, const float* __restrict__ r,
                         const float* __restrict__ g, const float* __restrict__ b) {
    __shared__ float red[4];
    int n = blockIdx.x, d = threadIdx.x;
    float x = h[n * DD + d] + r[n * DD + d];
    float v = x;
    for (int m = 32; m >= 1; m >>= 1) v += __shfl_xor(v, m, 64);
    if ((d & 63) == 0) red[d >> 6] = v;
    __syncthreads();
    float mu = (red[0] + red[1] + red[2] + red[3]) * (1.0f / 256.0f);
    __syncthreads();
    float t = x - mu;
    v = t * t;
    for (int m = 32; m >= 1; m >>= 1) v += __shfl_xor(v, m, 64);
    if ((d & 63) == 0) red[d >> 6] = v;
    __syncthreads();
    float var = (red[0] + red[1] + red[2] + red[3]) * (1.0f / 256.0f);
    h[n * DD + d] = t * rsqrtf(var + 1e-5f) * g[d] + b[d];
}

__global__ void k_out(const float* __restrict__ h, float* __restrict__ out) {
    int i = blockIdx.x * 256 + threadIdx.x;
    if (i < NN * DD) out[i] = h[i];
}

// ---------------- launch ----------------

extern "C" void kernel_launch(void* const* d_in, const int* in_sizes, int n_in,
                              void* d_out, int out_size, void* d_ws, size_t ws_size,
                              hipStream_t stream) {
    const int* atom_types = (const int*)d_in[0];
    const float* lattices = (const float*)d_in[1];
    const float* frac = (const float*)d_in[2];
    const int* eidx = (const int*)d_in[3];
    const float* shifts = (const float*)d_in[4];
    const int* batch_ids = (const int*)d_in[5];
    const float* atom_emb = (const float*)d_in[6];
    const float* node_W = (const float*)d_in[7];
    const float* node_b = (const float*)d_in[8];
    const float* edge_W = (const float*)d_in[9];
    const float* edge_b = (const float*)d_in[10];
    const float* Wq = (const float*)d_in[11];
    const float* bq = (const float*)d_in[12];
    const float* Wkv = (const float*)d_in[13];
    const float* bkv = (const float*)d_in[14];
    const float* Wo = (const float*)d_in[15];
    const float* bo = (const float*)d_in[16];
    const float* ln1g = (const float*)d_in[17];
    const float* ln1b = (const float*)d_in[18];
    const float* W1 = (const float*)d_in[19];
    const float* b1 = (const float*)d_in[20];
    const float* W2 = (const float*)d_in[21];
    const float* b2w = (const float*)d_in[22];
    const float* ln2g = (const float*)d_in[23];
    const float* ln2b = (const float*)d_in[24];

    char* base = (char*)d_ws;
    size_t off = 0;
    auto alloc = [&](size_t bytes) -> void* {
        void* p = base + off;
        off = (off + bytes + 255) & ~(size_t)255;
        return p;
    };
    // ~59 MB total
    int* counts = (int*)alloc((size_t)NN * 4);
    int* cursor = (int*)alloc((size_t)NN * 4);
    int* starts = (int*)alloc((size_t)(NN + 1) * 4);
    int* eids = (int*)alloc((size_t)EE * 4);
    float* lfeat = (float*)alloc((size_t)BB * 6 * 4);
    float* h_n = (float*)alloc((size_t)NN * DD * 4);
    float* attn = (float*)alloc((size_t)NN * DD * 4);
    float* tmp = (float*)alloc((size_t)NN * DD * 4);
    float* scores = tmp;  // disjoint lifetimes within a layer
    bf16* hnb = (bf16*)alloc((size_t)NN * DD * 2);
    bf16* attnb = (bf16*)alloc((size_t)NN * DD * 2);
    bf16* h1b = (bf16*)alloc((size_t)NN * 1024 * 2);
    bf16* WeP = (bf16*)alloc((size_t)19 * 8192 * 2);
    bf16* QP = (bf16*)alloc((size_t)LL * 16 * 8192 * 2);
    bf16* KP = (bf16*)alloc((size_t)LL * 16 * 8192 * 2);
    bf16* VP = (bf16*)alloc((size_t)LL * 16 * 8192 * 2);
    bf16* WoP = (bf16*)alloc((size_t)LL * 8 * 8192 * 2);
    bf16* W1P = (bf16*)alloc((size_t)LL * 32 * 8192 * 2);
    bf16* W2P = (bf16*)alloc((size_t)LL * 32 * 8192 * 2);

    const int* src = eidx;
    const int* dstp = eidx + EE;

    k_lfeat<<<1, 96, 0, stream>>>(lattices, lfeat);
    k_zero<<<(NN + 255) / 256, 256, 0, stream>>>(counts, NN);
    k_count<<<(EE + 255) / 256, 256, 0, stream>>>(src, counts);
    k_scan<<<1, 256, 0, stream>>>(counts, starts, cursor);
    k_scatter<<<(EE + 255) / 256, 256, 0, stream>>>(src, cursor, eids);
    k_node_init<<<NN, 256, 0, stream>>>(atom_types, batch_ids, atom_emb, node_W, node_b,
                                        lfeat, h_n);
    k_cvt<<<(NN * DD + 255) / 256, 256, 0, stream>>>(h_n, hnb, NN * DD);

    k_panel<<<dim3(19, 1, 1), 256, 0, stream>>>(edge_W, 256, 0, 0, KF, WeP, 19);
    k_panel<<<dim3(16, LL, 1), 256, 0, stream>>>(Wq, 256, 0, 512 * 256, 512, QP, 16);
    k_panel<<<dim3(16, LL, 1), 256, 0, stream>>>(Wkv, 512, 0, 512 * 512, 512, KP, 16);
    k_panel<<<dim3(16, LL, 1), 256, 0, stream>>>(Wkv, 512, 256, 512 * 512, 512, VP, 16);
    k_panel<<<dim3(8, LL, 1), 256, 0, stream>>>(Wo, 256, 0, 256 * 256, 256, WoP, 8);
    k_panel<<<dim3(8, LL, 4), 256, 0, stream>>>(W1, 1024, 0, 256 * 1024, 256, W1P, 8);
    k_panel<<<dim3(32, LL, 1), 256, 0, stream>>>(W2, 256, 0, 1024 * 256, 1024, W2P, 32);

    for (int l = 0; l < LL; l++) {
        const uint4* QPl = (const uint4*)(QP + (size_t)l * 16 * 8192);
        const uint4* KPl = (const uint4*)(KP + (size_t)l * 16 * 8192);
        const uint4* VPl = (const uint4*)(VP + (size_t)l * 16 * 8192);
        const uint4* WoPl = (const uint4*)(WoP + (size_t)l * 8 * 8192);
        const uint4* W1Pl = (const uint4*)(W1P + (size_t)l * 32 * 8192);
        const uint4* W2Pl = (const uint4*)(W2P + (size_t)l * 32 * 8192);
        const float* bql = bq + l * 256;
        const float* bkvl = bkv + l * 512;

        k_qk_mfma<<<EE / 64, 256, 0, stream>>>(hnb, src, dstp, frac, shifts,
                                               (const uint4*)WeP, edge_b, QPl, KPl,
                                               bql, bkvl, scores);
        k_softmax<<<NN, 256, 0, stream>>>(starts, eids, scores);
        k_zerof<<<(NN * DD + 255) / 256, 256, 0, stream>>>(attn, NN * DD);
        k_av_mfma<<<EE / 64, 256, 0, stream>>>(hnb, src, dstp, frac, shifts,
                                               (const uint4*)WeP, edge_b, VPl,
                                               bkvl, scores, attn);
        k_cvt<<<(NN * DD + 255) / 256, 256, 0, stream>>>(attn, attnb, NN * DD);
        k_gnode<0><<<dim3(NN / 32, 1), 128, 0, stream>>>(attnb, 256, WoPl, 8,
                                                         bo + l * 256, 0, tmp, nullptr, 256);
        k_add_ln<<<NN, 256, 0, stream>>>(h_n, tmp, ln1g + l * 256, ln1b + l * 256);
        k_cvt<<<(NN * DD + 255) / 256, 256, 0, stream>>>(h_n, hnb, NN * DD);
        k_gnode<1><<<dim3(NN / 32, 4), 128, 0, stream>>>(hnb, 256, W1Pl, 8,
                                                         b1 + l * 1024, 1, nullptr, h1b, 1024);
        k_gnode<0><<<dim3(NN / 32, 1), 128, 0, stream>>>(h1b, 1024, W2Pl, 32,
                                                         b2w + l * 256, 0, tmp, nullptr, 256);
        k_add_ln<<<NN, 256, 0, stream>>>(h_n, tmp, ln2g + l * 256, ln2b + l * 256);
        k_cvt<<<(NN * DD + 255) / 256, 256, 0, stream>>>(h_n, hnb, NN * DD);
    }
    k_out<<<(NN * DD + 255) / 256, 256, 0, stream>>>(h_n, (float*)d_out);
}